// Round 1
// baseline (70634.009 us; speedup 1.0000x reference)
//
#include <hip/hip_runtime.h>
#include <math.h>

#define BATCH 64
#define FD 128
#define HD 512
#define TFS 16
#define NSTEP 255
#define TOTAL 256
#define NWGD 256        // workgroups per direction
#define BS 16           // batch rows per wg (4 batch groups)
#define JS 8            // h-columns per wg (64 column groups)
#define THREADS 256
#define SAS 516         // LDS act stride in floats (pad to break bank conflicts)

// workspace layout (float offsets)
#define WS_XIN 64
#define WS_H0  (WS_XIN + 2*TFS*BATCH*FD)      // [dir][buf][b][j]
#define WS_H1  (WS_H0 + 4*BATCH*HD)
#define WS_XC  (WS_H1 + 4*BATCH*HD)           // [dir][b][f]
#define WS_END (WS_XC + 2*BATCH*FD)

__device__ __forceinline__ float sigm(float v) { return 1.0f / (1.0f + __expf(-v)); }

// per-direction chip-wide barrier: monotonic count + generation flag.
__device__ __forceinline__ void dir_barrier(unsigned* cnt, unsigned* gen, unsigned target) {
    __syncthreads();
    if (threadIdx.x == 0) {
        __builtin_amdgcn_fence(__ATOMIC_RELEASE, "agent");
        unsigned prev = __hip_atomic_fetch_add(cnt, 1u, __ATOMIC_ACQ_REL, __HIP_MEMORY_SCOPE_AGENT);
        if (prev + 1u == target * (unsigned)NWGD) {
            __hip_atomic_store(gen, target, __ATOMIC_RELEASE, __HIP_MEMORY_SCOPE_AGENT);
        } else {
            for (;;) {
                unsigned g = __hip_atomic_load(gen, __ATOMIC_RELAXED, __HIP_MEMORY_SCOPE_AGENT);
                if (g >= target) break;
                __builtin_amdgcn_s_sleep(1);
            }
        }
        __builtin_amdgcn_fence(__ATOMIC_ACQUIRE, "agent");
    }
    __syncthreads();
}

__device__ __forceinline__ void stage512(float* act, const float* __restrict__ src, int b0g, int tid) {
    int q = tid;
#pragma unroll
    for (int r = 0; r < 8; ++r, q += THREADS) {
        int b = q >> 7, c4 = q & 127;
        *(float4*)(act + b * SAS + c4 * 4) =
            *(const float4*)(src + (size_t)(b0g + b) * HD + c4 * 4);
    }
}

__device__ __forceinline__ void accum512(const float* act, const float* __restrict__ W,
                                         int row0, int row1, int bl, float& a0, float& a1) {
    const float4* w0p = (const float4*)(W + (size_t)row0 * HD);
    const float4* w1p = (const float4*)(W + (size_t)row1 * HD);
    const float4* ap  = (const float4*)(act + bl * SAS);
#pragma unroll 8
    for (int k = 0; k < HD / 4; ++k) {
        float4 a = ap[k], u = w0p[k], v = w1p[k];
        a0 = fmaf(u.x, a.x, fmaf(u.y, a.y, fmaf(u.z, a.z, fmaf(u.w, a.w, a0))));
        a1 = fmaf(v.x, a.x, fmaf(v.y, a.y, fmaf(v.z, a.z, fmaf(v.w, a.w, a1))));
    }
}

__global__ __launch_bounds__(THREADS, 2)
void md_lstm_kernel(const float* __restrict__ x,
                    const float* __restrict__ Wih0, const float* __restrict__ Whh0,
                    const float* __restrict__ bih0, const float* __restrict__ bhh0,
                    const float* __restrict__ Wih1, const float* __restrict__ Whh1,
                    const float* __restrict__ bih1, const float* __restrict__ bhh1,
                    const float* __restrict__ outW, const float* __restrict__ outB,
                    float* __restrict__ out, float* __restrict__ ws)
{
    const int tid = threadIdx.x;
    const int dir = (int)(blockIdx.x & 1);
    const int wid = (int)(blockIdx.x >> 1);   // 0..255 within direction
    const int bg  = wid >> 6;                 // batch group 0..3
    const int nb  = wid & 63;                 // column group 0..63

    unsigned* cnt = (unsigned*)ws + dir * 32;
    unsigned* gen = (unsigned*)ws + dir * 32 + 16;

    float* Xin = ws + WS_XIN + dir * (TFS * BATCH * FD);
    float* H0  = ws + WS_H0  + dir * (2 * BATCH * HD);
    float* H1  = ws + WS_H1  + dir * (2 * BATCH * HD);
    float* XC  = ws + WS_XC  + dir * (BATCH * FD);

    __shared__ float act[BS * SAS];

    unsigned bt = 0;

    // ---------------- prologue: build Xin for this direction, write endpoint outputs
    {
        int idx = wid * THREADS + tid;                 // 65536 threads/dir, 32768 float4s
        if (idx < TFS * BATCH * FD / 4) {
            int s  = idx >> 11;
            int r  = idx & 2047;
            int b  = r >> 5;
            int c4 = r & 31;
            const float4 raw = *(const float4*)(x + ((size_t)b * 32 + (dir ? (31 - s) : s)) * FD + c4 * 4);
            float sgn = (dir && c4 >= 16) ? -1.0f : 1.0f;   // vflip for backward dir
            float4 v = make_float4(raw.x * sgn, raw.y * sgn, raw.z * sgn, raw.w * sgn);
            *(float4*)(Xin + ((size_t)s * BATCH + b) * FD + c4 * 4) = v;
            if (s == 0) {
                // endpoint: forward idx 0 (w=1), backward idx 255 (w=1); both contribute raw x
                int oidx = dir ? (TOTAL - 1) : 0;
                float* op = out + ((size_t)b * TOTAL + oidx) * FD + c4 * 4;
                atomicAdd(op + 0, raw.x);
                atomicAdd(op + 1, raw.y);
                atomicAdd(op + 2, raw.z);
                atomicAdd(op + 3, raw.w);
            }
        }
    }
    ++bt; dir_barrier(cnt, gen, bt);

    // ---------------- per-thread constant mappings
    const int b0g = bg * BS;
    const int gp = tid & 1;             // gate pair: 0 -> (i,f), 1 -> (g,o)
    const int jj = (tid >> 1) & 7;
    const int bl = tid >> 4;            // 0..15 local batch
    const int bmine = b0g + bl;
    const int jmine = nb * JS + jj;
    const int row0 = (2 * gp) * HD + jmine;
    const int row1 = (2 * gp + 1) * HD + jmine;

    const float bia0 = bih0[row0] + bhh0[row0];
    const float bia1 = bih0[row1] + bhh0[row1];
    const float bib0 = bih1[row0] + bhh1[row0];
    const float bib1 = bih1[row1] + bhh1[row1];

    // Phase C mapping: 32 (b,f) pairs x 8 k-chunks
    const int pc_kc = tid & 7;
    const int pc_pair = tid >> 3;
    const int pc_b = b0g + (pc_pair >> 1);
    const int pc_f = nb * 2 + (pc_pair & 1);
    const float pc_ob = outB[pc_f];
    const float pc_sgn = (dir && pc_f >= 64) ? -1.0f : 1.0f;

    float creg0 = 0.0f, creg1 = 0.0f;   // cell states live in registers (gp==0 threads)

    for (int s = 0; s < NSTEP; ++s) {
        const float* xin = (s < TFS) ? (Xin + (size_t)s * BATCH * FD) : XC;
        float*       h0w = H0 + (s & 1) * BATCH * HD;
        const float* h0r = H0 + ((s + 1) & 1) * BATCH * HD;
        float*       h1w = H1 + (s & 1) * BATCH * HD;
        const float* h1r = H1 + ((s + 1) & 1) * BATCH * HD;

        // ---------------- Phase A: layer0 gates  g0 = x@Wih0^T + h0@Whh0^T + b
        float a0 = bia0, a1 = bia1;
        {   // stage x tile (16 x 128)
            int q = tid;
#pragma unroll
            for (int r = 0; r < 2; ++r, q += THREADS) {
                int b = q >> 5, c4 = q & 31;
                *(float4*)(act + b * SAS + c4 * 4) =
                    *(const float4*)(xin + (size_t)(b0g + b) * FD + c4 * 4);
            }
        }
        __syncthreads();
        {
            const float4* w0p = (const float4*)(Wih0 + (size_t)row0 * FD);
            const float4* w1p = (const float4*)(Wih0 + (size_t)row1 * FD);
            const float4* ap  = (const float4*)(act + bl * SAS);
#pragma unroll 8
            for (int k = 0; k < FD / 4; ++k) {
                float4 a = ap[k], u = w0p[k], v = w1p[k];
                a0 = fmaf(u.x, a.x, fmaf(u.y, a.y, fmaf(u.z, a.z, fmaf(u.w, a.w, a0))));
                a1 = fmaf(v.x, a.x, fmaf(v.y, a.y, fmaf(v.z, a.z, fmaf(v.w, a.w, a1))));
            }
        }
        __syncthreads();
        stage512(act, h0r, b0g, tid);
        __syncthreads();
        accum512(act, Whh0, row0, row1, bl, a0, a1);
        {
            float og0 = __shfl_xor(a0, 1);
            float og1 = __shfl_xor(a1, 1);
            if (gp == 0) {   // a0=i, a1=f, og0=g, og1=o
                float cn = sigm(a1) * creg0 + sigm(a0) * tanhf(og0);
                creg0 = cn;
                h0w[(size_t)bmine * HD + jmine] = sigm(og1) * tanhf(cn);
            }
        }
        ++bt; dir_barrier(cnt, gen, bt);

        // ---------------- Phase B: layer1 gates  g1 = h0new@Wih1^T + h1@Whh1^T + b
        float b0a = bib0, b1a = bib1;
        stage512(act, h0w, b0g, tid);
        __syncthreads();
        accum512(act, Wih1, row0, row1, bl, b0a, b1a);
        __syncthreads();
        stage512(act, h1r, b0g, tid);
        __syncthreads();
        accum512(act, Whh1, row0, row1, bl, b0a, b1a);
        {
            float og0 = __shfl_xor(b0a, 1);
            float og1 = __shfl_xor(b1a, 1);
            if (gp == 0) {
                float cn = sigm(b1a) * creg1 + sigm(b0a) * tanhf(og0);
                creg1 = cn;
                h1w[(size_t)bmine * HD + jmine] = sigm(og1) * tanhf(cn);
            }
        }
        ++bt; dir_barrier(cnt, gen, bt);

        // ---------------- Phase C: x_new = x + h1@outW^T + out_b ; emit blended output
        {
            const float4* hv = (const float4*)(h1w + (size_t)pc_b * HD);
            const float4* wv = (const float4*)(outW + (size_t)pc_f * HD);
            float p = 0.0f;
#pragma unroll
            for (int k = 0; k < 16; ++k) {
                float4 hh = hv[pc_kc * 16 + k], wwv = wv[pc_kc * 16 + k];
                p = fmaf(hh.x, wwv.x, fmaf(hh.y, wwv.y, fmaf(hh.z, wwv.z, fmaf(hh.w, wwv.w, p))));
            }
            p += __shfl_down(p, 4);
            p += __shfl_down(p, 2);
            p += __shfl_down(p, 1);
            if (pc_kc == 0) {
                float xold = xin[(size_t)pc_b * FD + pc_f];
                float xn = xold + pc_ob + p;
                XC[(size_t)pc_b * FD + pc_f] = xn;
                int oidx = dir ? (254 - s) : (s + 1);
                float wgt = (float)(254 - s) * (1.0f / 255.0f);
                atomicAdd(out + ((size_t)pc_b * TOTAL + oidx) * FD + pc_f, wgt * xn * pc_sgn);
            }
        }
        ++bt; dir_barrier(cnt, gen, bt);
    }
}

extern "C" void kernel_launch(void* const* d_in, const int* in_sizes, int n_in,
                              void* d_out, int out_size, void* d_ws, size_t ws_size,
                              hipStream_t stream) {
    const float* x    = (const float*)d_in[1];
    const float* Wih0 = (const float*)d_in[2];
    const float* Whh0 = (const float*)d_in[3];
    const float* bih0 = (const float*)d_in[4];
    const float* bhh0 = (const float*)d_in[5];
    const float* Wih1 = (const float*)d_in[6];
    const float* Whh1 = (const float*)d_in[7];
    const float* bih1 = (const float*)d_in[8];
    const float* bhh1 = (const float*)d_in[9];
    const float* outW = (const float*)d_in[10];
    const float* outB = (const float*)d_in[11];
    float* out = (float*)d_out;
    float* ws  = (float*)d_ws;

    hipMemsetAsync(d_out, 0, (size_t)out_size * sizeof(float), stream);
    hipMemsetAsync(d_ws, 0, (size_t)WS_END * sizeof(float), stream);

    md_lstm_kernel<<<dim3(2 * NWGD), dim3(THREADS), 0, stream>>>(
        x, Wih0, Whh0, bih0, bhh0, Wih1, Whh1, bih1, bhh1, outW, outB, out, ws);
}

// Round 2
// 31779.321 us; speedup vs baseline: 2.2226x; 2.2226x over previous
//
#include <hip/hip_runtime.h>
#include <math.h>

#define BATCH 64
#define FD 128
#define HD 512
#define TFS 16
#define NSTEP 255
#define TOTAL 256
#define NWGD2 128          // workgroups per direction
#define THREADS 512

// workspace float offsets
#define WS_ATOM 0
#define WS_XIN  1024
#define WS_H0   (WS_XIN + 2*TFS*BATCH*FD)     // [dir][buf][b][j]
#define WS_H1   (WS_H0 + 4*BATCH*HD)
#define WS_XC   (WS_H1 + 4*BATCH*HD)          // [dir][b][f]
#define WS_END  (WS_XC + 2*BATCH*FD)

__device__ __forceinline__ float sigm(float v) { return 1.0f / (1.0f + __expf(-v)); }

// per-direction chip-wide barrier, slot-rotating (16 slots), 128 arrivals.
__device__ __forceinline__ void dir_barrier(unsigned* cnt, unsigned* gen, unsigned bt) {
    __syncthreads();
    if (threadIdx.x == 0) {
        const unsigned slot = (bt & 15u) * 16u;
        __builtin_amdgcn_fence(__ATOMIC_RELEASE, "agent");
        unsigned prev = __hip_atomic_fetch_add(&cnt[slot], 1u, __ATOMIC_ACQ_REL, __HIP_MEMORY_SCOPE_AGENT);
        if (prev + 1u == (unsigned)NWGD2) {
            __hip_atomic_store(&cnt[slot], 0u, __ATOMIC_RELAXED, __HIP_MEMORY_SCOPE_AGENT);
            __hip_atomic_store(&gen[slot], bt, __ATOMIC_RELEASE, __HIP_MEMORY_SCOPE_AGENT);
        } else {
            int it = 0;
            for (;;) {
                unsigned g = __hip_atomic_load(&gen[slot], __ATOMIC_RELAXED, __HIP_MEMORY_SCOPE_AGENT);
                if (g >= bt) break;
                if (it < 4) __builtin_amdgcn_s_sleep(1);
                else        __builtin_amdgcn_s_sleep(16);
                ++it;
            }
        }
        __builtin_amdgcn_fence(__ATOMIC_ACQUIRE, "agent");
    }
    __syncthreads();
}

// One matmul phase: gates[rows][64b] = [srcA | srcB] @ [WA | WB]^T  (K split across 8 waves,
// per-wave private LDS chunk double-buffer, lane = batch, wave-uniform weight loads -> SMEM).
// Leaves per-wave partials folded into partialLDS[r*256 + w4*64 + b] (w4 = 0..3 after fold).
template<int ROWS>
__device__ __forceinline__ void mm_phase(
    const float* __restrict__ srcA, int strideA, int KA,
    const float* __restrict__ srcB, int strideB, int KB2,
    const float* __restrict__ WA, const float* __restrict__ WB,
    int wid, float* __restrict__ chunkLDS, float* __restrict__ partialLDS)
{
    const int tid = threadIdx.x;
    const int w = tid >> 6;
    const int l = tid & 63;
    const int K = KA + KB2;
    const int kb = K >> 3;          // per-wave K block
    const int nch = kb >> 3;        // 8-k chunks per wave
    const int kbase = w * kb;
    float* buf = chunkLDS + w * 1024;   // [2][8][64]
    const int sb = l >> 1;          // staging batch row 0..31 (and +32)
    const int fh = l & 1;           // staging k-half

    float acc[ROWS];
#pragma unroll
    for (int r = 0; r < ROWS; ++r) acc[r] = 0.f;

    // prologue: load + store chunk 0
    float4 r0, r1;
    {
        const int k0 = kbase;
        const float* pa = (k0 < KA) ? (srcA + (size_t)sb * strideA + k0)
                                    : (srcB + (size_t)sb * strideB + (k0 - KA));
        const float* pb = (k0 < KA) ? (srcA + (size_t)(sb + 32) * strideA + k0)
                                    : (srcB + (size_t)(sb + 32) * strideB + (k0 - KA));
        r0 = *(const float4*)(pa + fh * 4);
        r1 = *(const float4*)(pb + fh * 4);
        const int kk = fh * 4;
        buf[(kk+0)*64 + sb] = r0.x; buf[(kk+1)*64 + sb] = r0.y;
        buf[(kk+2)*64 + sb] = r0.z; buf[(kk+3)*64 + sb] = r0.w;
        buf[(kk+0)*64 + sb+32] = r1.x; buf[(kk+1)*64 + sb+32] = r1.y;
        buf[(kk+2)*64 + sb+32] = r1.z; buf[(kk+3)*64 + sb+32] = r1.w;
    }

    for (int c = 0; c < nch; ++c) {
        const int k0 = kbase + c * 8;
        if (c + 1 < nch) {  // prefetch next chunk (global), hidden under FMAs
            const int kn = k0 + 8;
            const float* pa = (kn < KA) ? (srcA + (size_t)sb * strideA + kn)
                                        : (srcB + (size_t)sb * strideB + (kn - KA));
            const float* pb = (kn < KA) ? (srcA + (size_t)(sb + 32) * strideA + kn)
                                        : (srcB + (size_t)(sb + 32) * strideB + (kn - KA));
            r0 = *(const float4*)(pa + fh * 4);
            r1 = *(const float4*)(pb + fh * 4);
        }
        // consume current chunk: lane = batch
        float a[8];
        {
            const float* bb = buf + (c & 1) * 512;
#pragma unroll
            for (int j = 0; j < 8; ++j) a[j] = bb[j*64 + l];
        }
        const float* Wbase; int wstr;
        if (k0 < KA) { Wbase = WA + k0;        wstr = KA;  }
        else         { Wbase = WB + (k0 - KA); wstr = KB2; }
#pragma unroll
        for (int r = 0; r < ROWS; ++r) {
            const int rowg = (ROWS == 16) ? ((r & 3) * HD + wid * 4 + (r >> 2)) : wid;
            const float* Wr = Wbase + (size_t)rowg * wstr;   // wave-uniform -> s_load
            float s0 = fmaf(Wr[0], a[0], fmaf(Wr[1], a[1], fmaf(Wr[2], a[2], Wr[3] * a[3])));
            float s1 = fmaf(Wr[4], a[4], fmaf(Wr[5], a[5], fmaf(Wr[6], a[6], Wr[7] * a[7])));
            acc[r] += s0 + s1;
        }
        if (c + 1 < nch) {  // stage next chunk into the other buffer
            float* nb = buf + ((c + 1) & 1) * 512;
            const int kk = fh * 4;
            nb[(kk+0)*64 + sb] = r0.x; nb[(kk+1)*64 + sb] = r0.y;
            nb[(kk+2)*64 + sb] = r0.z; nb[(kk+3)*64 + sb] = r0.w;
            nb[(kk+0)*64 + sb+32] = r1.x; nb[(kk+1)*64 + sb+32] = r1.y;
            nb[(kk+2)*64 + sb+32] = r1.z; nb[(kk+3)*64 + sb+32] = r1.w;
        }
    }

    // cross-wave partial fold: waves 0-3 write, waves 4-7 add
    if (w < 4) {
#pragma unroll
        for (int r = 0; r < ROWS; ++r) partialLDS[r*256 + w*64 + l] = acc[r];
    }
    __syncthreads();
    if (w >= 4) {
#pragma unroll
        for (int r = 0; r < ROWS; ++r) partialLDS[r*256 + (w-4)*64 + l] += acc[r];
    }
    __syncthreads();
}

__global__ __launch_bounds__(THREADS, 2)
void md_lstm_kernel(const float* __restrict__ x,
                    const float* __restrict__ Wih0, const float* __restrict__ Whh0,
                    const float* __restrict__ bih0, const float* __restrict__ bhh0,
                    const float* __restrict__ Wih1, const float* __restrict__ Whh1,
                    const float* __restrict__ bih1, const float* __restrict__ bhh1,
                    const float* __restrict__ outW, const float* __restrict__ outB,
                    float* __restrict__ out, float* __restrict__ ws)
{
    __shared__ float chunkLDS[8 * 1024];    // 32 KB: 8 waves x 2 bufs x [8][64]
    __shared__ float partialLDS[4096];      // 16 KB: [16 rows][4][64 b]

    const int tid = threadIdx.x;
    const int bid = (int)blockIdx.x;
    const int dir = bid >> 7;               // 0..1
    const int wid = bid & 127;              // 0..127 within direction

    unsigned* cnt = (unsigned*)ws + dir * 512;
    unsigned* gen = (unsigned*)ws + dir * 512 + 256;

    float* Xin = ws + WS_XIN + dir * (TFS * BATCH * FD);
    float* H0  = ws + WS_H0  + dir * (2 * BATCH * HD);
    float* H1  = ws + WS_H1  + dir * (2 * BATCH * HD);
    float* XC  = ws + WS_XC  + dir * (BATCH * FD);

    // ---------- prologue: build Xin (flip+vflip for backward), write endpoint outputs
    {
        int idx = wid * THREADS + tid;      // 65536 threads per dir, 32768 float4s
        if (idx < TFS * BATCH * FD / 4) {
            int s  = idx >> 11;
            int r  = idx & 2047;
            int b  = r >> 5;
            int c4 = r & 31;
            const float4 raw = *(const float4*)(x + ((size_t)b * 32 + (dir ? (31 - s) : s)) * FD + c4 * 4);
            float sgn = (dir && c4 >= 16) ? -1.0f : 1.0f;
            *(float4*)(Xin + ((size_t)s * BATCH + b) * FD + c4 * 4) =
                make_float4(raw.x * sgn, raw.y * sgn, raw.z * sgn, raw.w * sgn);
            if (s == 0) {
                int oidx = dir ? (TOTAL - 1) : 0;
                float* op = out + ((size_t)b * TOTAL + oidx) * FD + c4 * 4;
                atomicAdd(op + 0, raw.x);
                atomicAdd(op + 1, raw.y);
                atomicAdd(op + 2, raw.z);
                atomicAdd(op + 3, raw.w);
            }
        }
    }

    // ---------- persistent per-thread state
    const int b_red = tid >> 2;     // for tid<256: batch
    const int u_red = tid & 3;      // hidden unit within wg's 4
    float creg0 = 0.f, creg1 = 0.f;
    float bA[4] = {0,0,0,0}, bB[4] = {0,0,0,0};
    if (tid < 256) {
#pragma unroll
        for (int g = 0; g < 4; ++g) {
            int rowg = g * HD + wid * 4 + u_red;
            bA[g] = bih0[rowg] + bhh0[rowg];
            bB[g] = bih1[rowg] + bhh1[rowg];
        }
    }
    const float outBias = outB[wid];
    const float sgnC = (dir && wid >= 64) ? -1.0f : 1.0f;

    unsigned bt = 0;
    ++bt; dir_barrier(cnt, gen, bt);

    for (int s = 0; s < NSTEP; ++s) {
        const float* xin = (s < TFS) ? (Xin + (size_t)s * BATCH * FD) : XC;
        float*       h0w = H0 + (s & 1) * BATCH * HD;
        const float* h0r = H0 + ((s + 1) & 1) * BATCH * HD;
        float*       h1w = H1 + (s & 1) * BATCH * HD;
        const float* h1r = H1 + ((s + 1) & 1) * BATCH * HD;

        // ---- Phase A: layer0 gates = [x | h0r] @ [Wih0 | Whh0]^T
        mm_phase<16>(xin, FD, FD, h0r, HD, HD, Wih0, Whh0, wid, chunkLDS, partialLDS);
        if (tid < 256) {
            float g[4];
#pragma unroll
            for (int gg = 0; gg < 4; ++gg) {
                const float* pp = partialLDS + (u_red * 4 + gg) * 256 + b_red;
                g[gg] = bA[gg] + pp[0] + pp[64] + pp[128] + pp[192];
            }
            float cn = sigm(g[1]) * creg0 + sigm(g[0]) * tanhf(g[2]);
            creg0 = cn;
            h0w[(size_t)b_red * HD + wid * 4 + u_red] = sigm(g[3]) * tanhf(cn);
        }
        ++bt; dir_barrier(cnt, gen, bt);

        // ---- Phase B: layer1 gates = [h0w | h1r] @ [Wih1 | Whh1]^T
        mm_phase<16>(h0w, HD, HD, h1r, HD, HD, Wih1, Whh1, wid, chunkLDS, partialLDS);
        if (tid < 256) {
            float g[4];
#pragma unroll
            for (int gg = 0; gg < 4; ++gg) {
                const float* pp = partialLDS + (u_red * 4 + gg) * 256 + b_red;
                g[gg] = bB[gg] + pp[0] + pp[64] + pp[128] + pp[192];
            }
            float cn = sigm(g[1]) * creg1 + sigm(g[0]) * tanhf(g[2]);
            creg1 = cn;
            h1w[(size_t)b_red * HD + wid * 4 + u_red] = sigm(g[3]) * tanhf(cn);
        }
        ++bt; dir_barrier(cnt, gen, bt);

        // ---- Phase C: proj row f=wid: p[b] = h1w[b] . outW[wid]
        mm_phase<1>(h1w, HD, HD, h1w, HD, 0, outW, outW, wid, chunkLDS, partialLDS);
        if (tid < 64) {
            int b = tid;
            float p = partialLDS[b] + partialLDS[64 + b] + partialLDS[128 + b] + partialLDS[192 + b];
            float xold = xin[(size_t)b * FD + wid];
            float xn = xold + outBias + p;
            XC[(size_t)b * FD + wid] = xn;
            int oidx = dir ? (254 - s) : (s + 1);
            float wgt = (float)(254 - s) * (1.0f / 255.0f);
            atomicAdd(out + ((size_t)b * TOTAL + oidx) * FD + wid, wgt * xn * sgnC);
        }
        ++bt; dir_barrier(cnt, gen, bt);
    }
}

extern "C" void kernel_launch(void* const* d_in, const int* in_sizes, int n_in,
                              void* d_out, int out_size, void* d_ws, size_t ws_size,
                              hipStream_t stream) {
    const float* x    = (const float*)d_in[1];
    const float* Wih0 = (const float*)d_in[2];
    const float* Whh0 = (const float*)d_in[3];
    const float* bih0 = (const float*)d_in[4];
    const float* bhh0 = (const float*)d_in[5];
    const float* Wih1 = (const float*)d_in[6];
    const float* Whh1 = (const float*)d_in[7];
    const float* bih1 = (const float*)d_in[8];
    const float* bhh1 = (const float*)d_in[9];
    const float* outW = (const float*)d_in[10];
    const float* outB = (const float*)d_in[11];
    float* out = (float*)d_out;
    float* ws  = (float*)d_ws;

    hipMemsetAsync(d_out, 0, (size_t)out_size * sizeof(float), stream);
    hipMemsetAsync(d_ws, 0, (size_t)WS_END * sizeof(float), stream);

    md_lstm_kernel<<<dim3(2 * NWGD2), dim3(THREADS), 0, stream>>>(
        x, Wih0, Whh0, bih0, bhh0, Wih1, Whh1, bih1, bhh1, outW, outB, out, ws);
}

// Round 4
// 15359.422 us; speedup vs baseline: 4.5987x; 2.0690x over previous
//
#include <hip/hip_runtime.h>
#include <math.h>

#define BATCH 64
#define FD 128
#define HD 512
#define TFS 16
#define NSTEP 255
#define TOTAL 256
#define NWGD 128           // workgroups per direction (256 total, 1/CU)
#define THREADS 512

// ws float offsets
#define WS_BAR_SUB 0
#define WS_BAR_MST (WS_BAR_SUB + 2*16*8*64)
#define WS_BAR_GEN (WS_BAR_MST + 2*16*64)
#define WS_XINT    (WS_BAR_GEN + 2*16*64)
#define WS_H0T     (WS_XINT + 2*TFS*FD*BATCH)
#define WS_H1T     (WS_H0T + 2*2*HD*BATCH)
#define WS_XCT     (WS_H1T + 2*2*HD*BATCH)
#define WS_END     (WS_XCT + 2*FD*BATCH)

__device__ __forceinline__ float sigm(float v) { return 1.0f / (1.0f + __expf(-v)); }

// per-direction chip-wide barrier: 8 sub-counters (own cache lines) -> master -> gen flag.
__device__ __forceinline__ void dir_barrier(float* wsf, int dir, int wid, unsigned bt) {
    __syncthreads();
    if (threadIdx.x == 0) {
        const unsigned slot = bt & 15u;
        unsigned* sub = (unsigned*)wsf + WS_BAR_SUB + ((dir * 16 + slot) * 8 + (wid & 7)) * 64;
        unsigned* mst = (unsigned*)wsf + WS_BAR_MST + (dir * 16 + slot) * 64;
        unsigned* gen = (unsigned*)wsf + WS_BAR_GEN + (dir * 16 + slot) * 64;
        __builtin_amdgcn_fence(__ATOMIC_RELEASE, "agent");
        unsigned p = __hip_atomic_fetch_add(sub, 1u, __ATOMIC_ACQ_REL, __HIP_MEMORY_SCOPE_AGENT);
        if (p + 1u == 16u) {
            __hip_atomic_store(sub, 0u, __ATOMIC_RELAXED, __HIP_MEMORY_SCOPE_AGENT);
            unsigned m = __hip_atomic_fetch_add(mst, 1u, __ATOMIC_ACQ_REL, __HIP_MEMORY_SCOPE_AGENT);
            if (m + 1u == 8u) {
                __hip_atomic_store(mst, 0u, __ATOMIC_RELAXED, __HIP_MEMORY_SCOPE_AGENT);
                __hip_atomic_store(gen, bt, __ATOMIC_RELEASE, __HIP_MEMORY_SCOPE_AGENT);
            }
        }
        int it = 0;
        for (;;) {
            unsigned g = __hip_atomic_load(gen, __ATOMIC_RELAXED, __HIP_MEMORY_SCOPE_AGENT);
            if (g >= bt) break;
            if (it < 8) { __builtin_amdgcn_s_sleep(1); }
            else        { __builtin_amdgcn_s_sleep(4); }
            ++it;
        }
        __builtin_amdgcn_fence(__ATOMIC_ACQUIRE, "agent");
    }
    __syncthreads();
}

// gates[ROWS][64b] += act @ W^T for this wave's K-slice.
// act element k: k<KA from actA[k*64+lane], else actB[(k-KA)*64+lane]  (transposed [k][b] layout).
// Weights from LDS (wave-uniform broadcast b128). Partials -> pOut[r*512 + w*64 + lane].
template<int ROWS, int KSTR>
__device__ __forceinline__ void mm_phase(
    const float* __restrict__ actA, int KA,
    const float* __restrict__ actB,
    const float* __restrict__ wlds,
    float* __restrict__ pOut)
{
    const int tid = threadIdx.x;
    const int w = tid >> 6, l = tid & 63;
    constexpr int NCH = KSTR / 8;
    const int kbase = w * KSTR;
    const float* wl = wlds + w * ROWS * KSTR;

    float acc[ROWS];
#pragma unroll
    for (int r = 0; r < ROWS; ++r) acc[r] = 0.f;

    float a0[8], a1[8];
    {   // chunk 0
        const int k0 = kbase;
        const float* bp = (k0 < KA) ? (actA + (size_t)k0 * 64) : (actB + (size_t)(k0 - KA) * 64);
#pragma unroll
        for (int j = 0; j < 8; ++j) a0[j] = bp[j * 64 + l];
    }
#pragma unroll 2
    for (int c = 0; c < NCH; ++c) {
        float* cur = (c & 1) ? a1 : a0;
        float* nxt = (c & 1) ? a0 : a1;
        if (c + 1 < NCH) {   // prefetch next chunk into regs (hidden under FMAs)
            const int kn = kbase + (c + 1) * 8;
            const float* bp = (kn < KA) ? (actA + (size_t)kn * 64) : (actB + (size_t)(kn - KA) * 64);
#pragma unroll
            for (int j = 0; j < 8; ++j) nxt[j] = bp[j * 64 + l];
        }
#pragma unroll
        for (int jj = 0; jj < 2; ++jj) {
#pragma unroll
            for (int r = 0; r < ROWS; ++r) {
                const float4 wv = *(const float4*)(wl + r * KSTR + c * 8 + jj * 4);
                acc[r] = fmaf(wv.x, cur[jj * 4 + 0], fmaf(wv.y, cur[jj * 4 + 1],
                         fmaf(wv.z, cur[jj * 4 + 2], fmaf(wv.w, cur[jj * 4 + 3], acc[r]))));
            }
        }
    }
#pragma unroll
    for (int r = 0; r < ROWS; ++r) pOut[r * 512 + w * 64 + l] = acc[r];
    __syncthreads();
}

__global__ __launch_bounds__(THREADS, 2)
void md_lstm_kernel(const float* __restrict__ x,
                    const float* __restrict__ Wih0, const float* __restrict__ Whh0,
                    const float* __restrict__ bih0, const float* __restrict__ bhh0,
                    const float* __restrict__ Wih1, const float* __restrict__ Whh1,
                    const float* __restrict__ bih1, const float* __restrict__ bhh1,
                    const float* __restrict__ outW, const float* __restrict__ outB,
                    float* __restrict__ out, float* __restrict__ ws)
{
    __shared__ __align__(16) float wA[16 * 640];     // [w][16r][80]   40 KB
    __shared__ __align__(16) float wB[16 * 1024];    // [w][16r][128]  64 KB
    __shared__ __align__(16) float wC[512];          // [w][64]         2 KB
    __shared__ __align__(16) float pLDS[16 * 512];   // [r][w][64]     32 KB

    const int tid = threadIdx.x;
    const int bid = (int)blockIdx.x;
    const int dir = bid >> 7;
    const int wid = bid & 127;

    float* XinT = ws + WS_XINT + dir * (TFS * FD * BATCH);
    float* H0T  = ws + WS_H0T  + dir * (2 * HD * BATCH);
    float* H1T  = ws + WS_H1T  + dir * (2 * HD * BATCH);
    float* XCT  = ws + WS_XCT  + dir * (FD * BATCH);

    // ---------- prologue 1: transposed Xin [s][f][b] + endpoint outputs
    for (int q = wid * THREADS + tid; q < TFS * FD * BATCH; q += NWGD * THREADS) {
        int b = q & 63, f = (q >> 6) & 127, s = q >> 13;
        int tsrc = dir ? (31 - s) : s;
        float raw = x[((size_t)b * 32 + tsrc) * FD + f];
        float sgn = (dir && f >= 64) ? -1.f : 1.f;
        XinT[((size_t)s * FD + f) * 64 + b] = raw * sgn;
        if (s == 0) {
            int oidx = dir ? (TOTAL - 1) : 0;
            atomicAdd(out + ((size_t)b * TOTAL + oidx) * FD + f, raw);
        }
    }

    // ---------- prologue 2: pin this wg's weight slice in LDS (once, ever)
    for (int idx = tid; idx < 16 * 640; idx += THREADS) {
        int r = idx / 640, k = idx % 640;
        int rowg = (r & 3) * HD + wid * 4 + (r >> 2);
        float v = (k < FD) ? Wih0[(size_t)rowg * FD + k] : Whh0[(size_t)rowg * HD + (k - FD)];
        wA[(k / 80) * 1280 + r * 80 + (k % 80)] = v;
    }
    for (int idx = tid; idx < 16 * 1024; idx += THREADS) {
        int r = idx >> 10, k = idx & 1023;
        int rowg = (r & 3) * HD + wid * 4 + (r >> 2);
        float v = (k < HD) ? Wih1[(size_t)rowg * HD + k] : Whh1[(size_t)rowg * HD + (k - HD)];
        wB[(k >> 7) * 2048 + r * 128 + (k & 127)] = v;
    }
    for (int idx = tid; idx < HD; idx += THREADS) {
        wC[idx] = outW[(size_t)wid * HD + idx];
    }
    __syncthreads();

    // ---------- persistent per-thread state
    const int u_red = tid >> 6;       // tid<256: hidden unit 0..3
    const int b_red = tid & 63;       // batch
    float creg0 = 0.f, creg1 = 0.f;
    float bA[4] = {0, 0, 0, 0}, bB[4] = {0, 0, 0, 0};
    if (tid < 256) {
#pragma unroll
        for (int g = 0; g < 4; ++g) {
            int rowg = g * HD + wid * 4 + u_red;
            bA[g] = bih0[rowg] + bhh0[rowg];
            bB[g] = bih1[rowg] + bhh1[rowg];
        }
    }
    const float outBias = outB[wid];
    const float sgnC = (dir && wid >= 64) ? -1.0f : 1.0f;

    unsigned bt = 0;
    ++bt; dir_barrier(ws, dir, wid, bt);

    for (int s = 0; s < NSTEP; ++s) {
        const float* xinT = (s < TFS) ? (XinT + (size_t)s * FD * 64) : XCT;
        float*       h0wT = H0T + (s & 1) * HD * 64;
        const float* h0rT = H0T + ((s + 1) & 1) * HD * 64;
        float*       h1wT = H1T + (s & 1) * HD * 64;
        const float* h1rT = H1T + ((s + 1) & 1) * HD * 64;

        // ---- Phase A: layer0 gates = [x | h0r] @ [Wih0|Whh0]^T
        mm_phase<16, 80>(xinT, FD, h0rT, wA, pLDS);
        if (tid < 256) {
            float g[4];
#pragma unroll
            for (int gg = 0; gg < 4; ++gg) {
                const float* pp = pLDS + (u_red * 4 + gg) * 512 + b_red;
                float t0 = pp[0] + pp[64], t1 = pp[128] + pp[192];
                float t2 = pp[256] + pp[320], t3 = pp[384] + pp[448];
                g[gg] = bA[gg] + (t0 + t1) + (t2 + t3);
            }
            float cn = sigm(g[1]) * creg0 + sigm(g[0]) * tanhf(g[2]);
            creg0 = cn;
            h0wT[(size_t)(wid * 4 + u_red) * 64 + b_red] = sigm(g[3]) * tanhf(cn);
        }
        ++bt; dir_barrier(ws, dir, wid, bt);

        // ---- Phase B: layer1 gates = [h0w | h1r] @ [Wih1|Whh1]^T
        mm_phase<16, 128>(h0wT, HD, h1rT, wB, pLDS);
        if (tid < 256) {
            float g[4];
#pragma unroll
            for (int gg = 0; gg < 4; ++gg) {
                const float* pp = pLDS + (u_red * 4 + gg) * 512 + b_red;
                float t0 = pp[0] + pp[64], t1 = pp[128] + pp[192];
                float t2 = pp[256] + pp[320], t3 = pp[384] + pp[448];
                g[gg] = bB[gg] + (t0 + t1) + (t2 + t3);
            }
            float cn = sigm(g[1]) * creg1 + sigm(g[0]) * tanhf(g[2]);
            creg1 = cn;
            h1wT[(size_t)(wid * 4 + u_red) * 64 + b_red] = sigm(g[3]) * tanhf(cn);
        }
        ++bt; dir_barrier(ws, dir, wid, bt);

        // ---- Phase C: proj row f=wid: p[b] = h1w[:,b] . outW[wid,:]
        mm_phase<1, 64>(h1wT, HD, h1wT, wC, pLDS);
        if (tid < 64) {
            int b = tid;
            float p = ((pLDS[b] + pLDS[64 + b]) + (pLDS[128 + b] + pLDS[192 + b]))
                    + ((pLDS[256 + b] + pLDS[320 + b]) + (pLDS[384 + b] + pLDS[448 + b]));
            float xold = xinT[(size_t)wid * 64 + b];
            float xn = xold + outBias + p;
            XCT[(size_t)wid * 64 + b] = xn;
            int oidx = dir ? (254 - s) : (s + 1);
            float wgt = (float)(254 - s) * (1.0f / 255.0f);
            atomicAdd(out + ((size_t)b * TOTAL + oidx) * FD + wid, wgt * xn * sgnC);
        }
        ++bt; dir_barrier(ws, dir, wid, bt);
    }
}

extern "C" void kernel_launch(void* const* d_in, const int* in_sizes, int n_in,
                              void* d_out, int out_size, void* d_ws, size_t ws_size,
                              hipStream_t stream) {
    const float* x    = (const float*)d_in[1];
    const float* Wih0 = (const float*)d_in[2];
    const float* Whh0 = (const float*)d_in[3];
    const float* bih0 = (const float*)d_in[4];
    const float* bhh0 = (const float*)d_in[5];
    const float* Wih1 = (const float*)d_in[6];
    const float* Whh1 = (const float*)d_in[7];
    const float* bih1 = (const float*)d_in[8];
    const float* bhh1 = (const float*)d_in[9];
    const float* outW = (const float*)d_in[10];
    const float* outB = (const float*)d_in[11];
    float* out = (float*)d_out;
    float* ws  = (float*)d_ws;

    (void)hipMemsetAsync(d_out, 0, (size_t)out_size * sizeof(float), stream);
    (void)hipMemsetAsync(d_ws, 0, (size_t)WS_END * sizeof(float), stream);

    md_lstm_kernel<<<dim3(2 * NWGD), dim3(THREADS), 0, stream>>>(
        x, Wih0, Whh0, bih0, bhh0, Wih1, Whh1, bih1, bhh1, outW, outB, out, ws);
}

// Round 6
// 12953.694 us; speedup vs baseline: 5.4528x; 1.1857x over previous
//
#include <hip/hip_runtime.h>
#include <math.h>

#define FD 128
#define HD 512
#define TFS 16
#define NSTEP 255
#define TOTAL 256
#define NWG 256
#define THREADS 1024

// ws dword offsets
#define WS_BAR_SUB 0                          // 16 slots x 8 subs x 16
#define WS_BAR_MST (WS_BAR_SUB + 16*8*16)     // 16 slots x 16
#define WS_BAR_GEN (WS_BAR_MST + 16*16)
#define WS_H0      (WS_BAR_GEN + 16*16)       // 2 bufs x [512 k][128 col]
#define WS_H1      (WS_H0 + 2*HD*128)
#define WS_X       (WS_H1 + 2*HD*128)         // [128 f][128 col] fp32 AR x-state
#define WS_XIN     (WS_X + FD*128)            // [16 s][128 f][128 col]
#define WS_M       (WS_XIN + TFS*FD*128)      // [2048 r][512 j] fused Wih0@outW
#define WS_END     (WS_M + 2048*HD)
#define WS_ZERO_DW WS_X                       // zero BAR + H0 + H1

__device__ __forceinline__ float sigm(float v) { return 1.0f / (1.0f + __expf(-v)); }

// chip-wide barrier: 8 XCD-local subs x 32 -> master 8 -> gen flag; slot-rotated.
__device__ __forceinline__ void grid_barrier(unsigned* wsp, int bid, unsigned bt) {
    __syncthreads();
    if (threadIdx.x == 0) {
        const unsigned slot = bt & 15u;
        unsigned* sub = wsp + WS_BAR_SUB + (slot * 8 + (bid & 7)) * 16;
        unsigned* mst = wsp + WS_BAR_MST + slot * 16;
        unsigned* gen = wsp + WS_BAR_GEN + slot * 16;
        __builtin_amdgcn_fence(__ATOMIC_RELEASE, "agent");
        unsigned p = __hip_atomic_fetch_add(sub, 1u, __ATOMIC_ACQ_REL, __HIP_MEMORY_SCOPE_AGENT);
        if (p + 1u == 32u) {
            __hip_atomic_store(sub, 0u, __ATOMIC_RELAXED, __HIP_MEMORY_SCOPE_AGENT);
            unsigned m = __hip_atomic_fetch_add(mst, 1u, __ATOMIC_ACQ_REL, __HIP_MEMORY_SCOPE_AGENT);
            if (m + 1u == 8u) {
                __hip_atomic_store(mst, 0u, __ATOMIC_RELAXED, __HIP_MEMORY_SCOPE_AGENT);
                __hip_atomic_store(gen, bt, __ATOMIC_RELEASE, __HIP_MEMORY_SCOPE_AGENT);
            }
        }
        int it = 0;
        for (;;) {
            unsigned g = __hip_atomic_load(gen, __ATOMIC_RELAXED, __HIP_MEMORY_SCOPE_AGENT);
            if (g >= bt) break;
            if (it < 8) { __builtin_amdgcn_s_sleep(1); } else { __builtin_amdgcn_s_sleep(4); }
            ++it;
        }
        __builtin_amdgcn_fence(__ATOMIC_ACQUIRE, "agent");
    }
    __syncthreads();
}

// acc[8 rows][2 cols] += W(8 x NCH*8, LDS broadcast) @ act(NCH*8 k x 2 cols, global)
template<int NCH>
__device__ __forceinline__ void gemv8(const float* __restrict__ act,  // + kslice*128 + 2*lane
                                      const float* __restrict__ wl,   // + k0
                                      const int wstr, float acc[8][2])
{
    float2 ab[2][8];
#pragma unroll
    for (int j = 0; j < 8; ++j) ab[0][j] = *(const float2*)(act + j * 128);
#pragma unroll
    for (int c = 0; c < NCH; ++c) {
        if (c + 1 < NCH) {
            const float* an = act + (size_t)(c + 1) * 1024;
#pragma unroll
            for (int j = 0; j < 8; ++j) ab[(c + 1) & 1][j] = *(const float2*)(an + j * 128);
        }
        const float2* cb = ab[c & 1];
#pragma unroll
        for (int r = 0; r < 8; ++r) {
            const float* wr = wl + r * wstr + c * 8;
            const float4 w0 = *(const float4*)wr;
            const float4 w1 = *(const float4*)(wr + 4);
            acc[r][0] = fmaf(w0.x, cb[0].x, acc[r][0]); acc[r][1] = fmaf(w0.x, cb[0].y, acc[r][1]);
            acc[r][0] = fmaf(w0.y, cb[1].x, acc[r][0]); acc[r][1] = fmaf(w0.y, cb[1].y, acc[r][1]);
            acc[r][0] = fmaf(w0.z, cb[2].x, acc[r][0]); acc[r][1] = fmaf(w0.z, cb[2].y, acc[r][1]);
            acc[r][0] = fmaf(w0.w, cb[3].x, acc[r][0]); acc[r][1] = fmaf(w0.w, cb[3].y, acc[r][1]);
            acc[r][0] = fmaf(w1.x, cb[4].x, acc[r][0]); acc[r][1] = fmaf(w1.x, cb[4].y, acc[r][1]);
            acc[r][0] = fmaf(w1.y, cb[5].x, acc[r][0]); acc[r][1] = fmaf(w1.y, cb[5].y, acc[r][1]);
            acc[r][0] = fmaf(w1.z, cb[6].x, acc[r][0]); acc[r][1] = fmaf(w1.z, cb[6].y, acc[r][1]);
            acc[r][0] = fmaf(w1.w, cb[7].x, acc[r][0]); acc[r][1] = fmaf(w1.w, cb[7].y, acc[r][1]);
        }
    }
}

// M = Wih0 [2048x128] @ outW [128x512]  -> ws M region
__global__ __launch_bounds__(512)
void build_m_kernel(const float* __restrict__ Wih0, const float* __restrict__ outW,
                    float* __restrict__ ws)
{
    __shared__ float wl[16 * 128];
    const int tid = threadIdx.x;
    const int rb = (int)blockIdx.x;          // 0..127, rows rb*16..+15
    for (int d = tid; d < 16 * 128; d += 512)
        wl[d] = Wih0[(size_t)(rb * 16 + (d >> 7)) * 128 + (d & 127)];
    __syncthreads();
    const int j = tid;                        // 0..511
    float acc[16];
#pragma unroll
    for (int r = 0; r < 16; ++r) acc[r] = 0.f;
    for (int f = 0; f < 128; ++f) {
        const float ov = outW[(size_t)f * 512 + j];
#pragma unroll
        for (int r = 0; r < 16; ++r) acc[r] = fmaf(wl[r * 128 + f], ov, acc[r]);
    }
    float* M = ws + WS_M;
#pragma unroll
    for (int r = 0; r < 16; ++r) M[(size_t)(rb * 16 + r) * 512 + j] = acc[r];
}

__global__ __launch_bounds__(THREADS)
void md_lstm_kernel(const float* __restrict__ x,
                    const float* __restrict__ Wih0, const float* __restrict__ Whh0,
                    const float* __restrict__ bih0, const float* __restrict__ bhh0,
                    const float* __restrict__ Wih1, const float* __restrict__ Whh1,
                    const float* __restrict__ bih1, const float* __restrict__ bhh1,
                    const float* __restrict__ outW, const float* __restrict__ outB,
                    float* __restrict__ out, float* __restrict__ ws)
{
    __shared__ __align__(16) float pLDS[16 * 8 * 128];  // 64 KB partials [wave][rl][col]
    __shared__ __align__(16) float wM[8 * 512];          // 16 KB
    __shared__ __align__(16) float wWhh0[8 * 512];       // 16 KB
    __shared__ __align__(16) float wWih0[8 * 128];       //  4 KB
    __shared__ __align__(16) float wL1[8 * 1024];        // 32 KB [Wih1|Whh1]
    __shared__ __align__(16) float wProj[512];           //  2 KB outW row fC
    __shared__ __align__(16) float projP[16 * 64];       //  4 KB
    __shared__ float outBl[128];

    const int tid = threadIdx.x;
    const int bid = (int)blockIdx.x;
    const int wid = bid;                      // wg owns units {2wid, 2wid+1}, rows rl=g*2+u
    const int wv = tid >> 6, l = tid & 63;
    const int wk = wv & 7;
    const int fC = wid >> 1;                  // proj feature owned
    const int cb0 = (wid & 1) * 64;           // proj col block

    unsigned* wsp = (unsigned*)ws;
    float* XinA = ws + WS_XIN;
    float* Xst  = ws + WS_X;
    const float* Mg = ws + WS_M;

    // ---------- prologue: Xin + endpoints
    {
        int q = bid * THREADS + tid;          // exactly 262144 = 16*128*128
        int col = q & 127, f = (q >> 7) & 127, s0 = q >> 14;
        int dirq = col & 1, b = col >> 1;
        int tsrc = dirq ? (31 - s0) : s0;
        float sgn = (dirq && f >= 64) ? -1.f : 1.f;
        XinA[(size_t)s0 * 16384 + f * 128 + col] = x[((size_t)b * 32 + tsrc) * FD + f] * sgn;
        if (q < 64 * 128) {
            int bb = q >> 7, ff = q & 127;
            out[((size_t)bb * TOTAL + 0) * FD + ff]   = x[((size_t)bb * 32 + 0) * FD + ff];
            out[((size_t)bb * TOTAL + 255) * FD + ff] = x[((size_t)bb * 32 + 31) * FD + ff];
        }
    }

    // ---------- stage weights to LDS
    for (int d = tid; d < 8 * 512; d += THREADS) {
        int rl = d >> 9, k = d & 511;
        int rg = (rl >> 1) * 512 + wid * 2 + (rl & 1);
        wM[d]    = Mg[(size_t)rg * 512 + k];
        wWhh0[d] = Whh0[(size_t)rg * 512 + k];
    }
    for (int d = tid; d < 8 * 128; d += THREADS) {
        int rl = d >> 7, k = d & 127;
        int rg = (rl >> 1) * 512 + wid * 2 + (rl & 1);
        wWih0[d] = Wih0[(size_t)rg * 128 + k];
    }
    for (int d = tid; d < 8 * 1024; d += THREADS) {
        int rl = d >> 10, k = d & 1023;
        int rg = (rl >> 1) * 512 + wid * 2 + (rl & 1);
        wL1[d] = (k < 512) ? Wih1[(size_t)rg * 512 + k] : Whh1[(size_t)rg * 512 + (k - 512)];
    }
    for (int d = tid; d < 512; d += THREADS) wProj[d] = outW[(size_t)fC * 512 + d];
    for (int d = tid; d < 128; d += THREADS) outBl[d] = outB[d];
    __syncthreads();

    // ---------- persistent per-thread state (tid<256: col = tid&127, u = tid>>7)
    const int colE = tid & 127, uE = tid >> 7;
    float c0 = 0.f, c1 = 0.f;
    float Greg[4] = {0, 0, 0, 0};
    float bA[4], bB[4], cvec[4];
    if (tid < 256) {
#pragma unroll
        for (int g = 0; g < 4; ++g) {
            int rg = g * 512 + wid * 2 + uE;
            bA[g] = bih0[rg] + bhh0[rg];
            bB[g] = bih1[rg] + bhh1[rg];
            int rl = g * 2 + uE;
            float cv = 0.f;
            for (int f = 0; f < 128; ++f) cv = fmaf(wWih0[rl * 128 + f], outBl[f], cv);
            cvec[g] = cv;
        }
    }
    const float outBias = outB[fC];

    unsigned bt = 0;
    ++bt; grid_barrier(wsp, bid, bt);

    for (int s = 0; s <= NSTEP; ++s) {
        const bool last = (s == NSTEP);
        const float* h1r = ws + WS_H1 + ((s + 1) & 1) * HD * 128;   // h1_{s-1}
        const float* h0r = ws + WS_H0 + ((s + 1) & 1) * HD * 128;   // h0_{s-1}
        float*       h0w = ws + WS_H0 + (s & 1) * HD * 128;
        float*       h1w = ws + WS_H1 + (s & 1) * HD * 128;

        // ---- proj partials for output emission s (uses h1_{s-1})
        if (s >= 1) {
            const float* hp = h1r + (size_t)(wv * 32) * 128 + cb0 + l;
            float p = 0.f;
#pragma unroll
            for (int k = 0; k < 32; ++k) p = fmaf(wProj[wv * 32 + k], hp[(size_t)k * 128], p);
            projP[wv * 64 + l] = p;
        }

        // ---- Phase A gemv
        if (!last) {
            float acc[8][2];
#pragma unroll
            for (int r = 0; r < 8; ++r) { acc[r][0] = 0.f; acc[r][1] = 0.f; }
            if (s < TFS) {
                if (wv < 8) gemv8<2>(XinA + (size_t)s * 16384 + (wk * 16) * 128 + 2 * l,
                                     wWih0 + wk * 16, 128, acc);
                else        gemv8<8>(h0r + (size_t)(wk * 64) * 128 + 2 * l,
                                     wWhh0 + wk * 64, 512, acc);
            } else {
                if (wv < 8) gemv8<8>(h1r + (size_t)(wk * 64) * 128 + 2 * l,
                                     wM + wk * 64, 512, acc);
                else        gemv8<8>(h0r + (size_t)(wk * 64) * 128 + 2 * l,
                                     wWhh0 + wk * 64, 512, acc);
            }
#pragma unroll
            for (int r = 0; r < 8; ++r)
                *(float2*)&pLDS[wv * 1024 + r * 128 + 2 * l] = make_float2(acc[r][0], acc[r][1]);
        }
        __syncthreads();

        // ---- output emission (position s)
        if (s >= 1 && tid < 64) {
            int col = cb0 + tid;
            float P = outBias;
#pragma unroll
            for (int w2 = 0; w2 < 16; ++w2) P += projP[w2 * 64 + tid];
            float xprev = (s - 1 < TFS) ? XinA[(size_t)(s - 1) * 16384 + fC * 128 + col]
                                        : Xst[(size_t)fC * 128 + col];
            float xn = xprev + P;
            if (s >= TFS) Xst[(size_t)fC * 128 + col] = xn;
            int dirq = col & 1, b = col >> 1;
            int oidx = dirq ? (255 - s) : s;
            float wgt = (float)(255 - s) * (1.0f / 255.0f);
            float sg = (dirq && fC >= 64) ? -1.f : 1.f;
            atomicAdd(out + ((size_t)b * TOTAL + oidx) * FD + fC, wgt * xn * sg);
        }
        if (last) break;

        // ---- Phase A finalize: gates -> h0_s
        if (tid < 256) {
            float g[4];
#pragma unroll
            for (int gg = 0; gg < 4; ++gg) {
                int rl = gg * 2 + uE;
                float ft = 0.f, fh = 0.f;
#pragma unroll
                for (int w2 = 0; w2 < 8; ++w2)  ft += pLDS[w2 * 1024 + rl * 128 + colE];
#pragma unroll
                for (int w2 = 8; w2 < 16; ++w2) fh += pLDS[w2 * 1024 + rl * 128 + colE];
                if (s < TFS) Greg[gg] = ft;
                else         Greg[gg] += ft + cvec[gg];
                g[gg] = Greg[gg] + fh + bA[gg];
            }
            float cn = sigm(g[1]) * c0 + sigm(g[0]) * tanhf(g[2]);
            c0 = cn;
            h0w[(size_t)(wid * 2 + uE) * 128 + colE] = sigm(g[3]) * tanhf(cn);
        }
        ++bt; grid_barrier(wsp, bid, bt);

        // ---- Phase B: layer1 gates = [h0_s | h1_{s-1}] @ [Wih1|Whh1]^T
        {
            float acc[8][2];
#pragma unroll
            for (int r = 0; r < 8; ++r) { acc[r][0] = 0.f; acc[r][1] = 0.f; }
            const float* srcB = (wv < 8) ? (h0w + (size_t)(wv * 64) * 128 + 2 * l)
                                         : (h1r + (size_t)((wv - 8) * 64) * 128 + 2 * l);
            gemv8<8>(srcB, wL1 + wv * 64, 1024, acc);
#pragma unroll
            for (int r = 0; r < 8; ++r)
                *(float2*)&pLDS[wv * 1024 + r * 128 + 2 * l] = make_float2(acc[r][0], acc[r][1]);
        }
        __syncthreads();
        if (tid < 256) {
            float g[4];
#pragma unroll
            for (int gg = 0; gg < 4; ++gg) {
                int rl = gg * 2 + uE;
                float fs = 0.f;
#pragma unroll
                for (int w2 = 0; w2 < 16; ++w2) fs += pLDS[w2 * 1024 + rl * 128 + colE];
                g[gg] = fs + bB[gg];
            }
            float cn = sigm(g[1]) * c1 + sigm(g[0]) * tanhf(g[2]);
            c1 = cn;
            h1w[(size_t)(wid * 2 + uE) * 128 + colE] = sigm(g[3]) * tanhf(cn);
        }
        ++bt; grid_barrier(wsp, bid, bt);
    }
}

extern "C" void kernel_launch(void* const* d_in, const int* in_sizes, int n_in,
                              void* d_out, int out_size, void* d_ws, size_t ws_size,
                              hipStream_t stream) {
    const float* x    = (const float*)d_in[1];
    const float* Wih0 = (const float*)d_in[2];
    const float* Whh0 = (const float*)d_in[3];
    const float* bih0 = (const float*)d_in[4];
    const float* bhh0 = (const float*)d_in[5];
    const float* Wih1 = (const float*)d_in[6];
    const float* Whh1 = (const float*)d_in[7];
    const float* bih1 = (const float*)d_in[8];
    const float* bhh1 = (const float*)d_in[9];
    const float* outW = (const float*)d_in[10];
    const float* outB = (const float*)d_in[11];
    float* out = (float*)d_out;
    float* ws  = (float*)d_ws;

    (void)hipMemsetAsync(d_out, 0, (size_t)out_size * sizeof(float), stream);
    (void)hipMemsetAsync(d_ws, 0, (size_t)WS_ZERO_DW * sizeof(float), stream);

    build_m_kernel<<<dim3(128), dim3(512), 0, stream>>>(Wih0, outW, ws);

    md_lstm_kernel<<<dim3(NWG), dim3(THREADS), 0, stream>>>(
        x, Wih0, Whh0, bih0, bhh0, Wih1, Whh1, bih1, bhh1, outW, outB, out, ws);
}